// Round 16
// baseline (1696.586 us; speedup 1.0000x reference)
//
#include <hip/hip_runtime.h>
#include <hip/hip_bf16.h>

// Problem dims
constexpr int NB = 128;   // batch
constexpr int NT = 512;   // seq len
constexpr int NE = 256;   // embed dim
constexpr int NH = 512;   // hidden
constexpr int NV = 64;    // vocab
constexpr int NP = 128;   // output proj dim

// Split-pipeline (r15-proven, 1547us) + overlapped polling (this round):
//   blocks [0,64):   L0(g,sl) — h0 recurrence;  blocks [64,128): L1(g,sl).
// Stage tail: wave 0 publishes slice + drains + stores flag (one wave's
// program order = r13's drain->flag guarantee) WHILE waves 2-3 poll the
// NEXT stage's sibling flags (own flag skipped -> no circular wait).
// Coherence recipe r13-proven: relaxed agent polls -> ACQUIRE agent fence
// (buffer_inv) -> sc1 loads (vmcnt inside asm clause) -> sc1 publishes.
constexpr int GROUPS = 8;
constexpr int MR     = 16;
constexpr int NCS    = 64;
constexpr int SLICES = 8;
constexpr int NBLK   = GROUPS * SLICES * 2;  // 128 blocks
constexpr int RING   = 16;                   // h0 ring depth
constexpr int FS     = 32;                   // flag stride (ints) = 128B line

typedef unsigned short u16;
typedef __attribute__((ext_vector_type(8))) short bf16x8v;
typedef __attribute__((ext_vector_type(4))) float f32x4v;
typedef __attribute__((ext_vector_type(4))) unsigned u32x4;

__device__ __forceinline__ u16 f2bf(float x) {
  unsigned u = __builtin_bit_cast(unsigned, x);
  return (u16)((u + 0x7fffu + ((u >> 16) & 1u)) >> 16);  // RNE
}

__device__ __forceinline__ void ld4_sc1(const void* p0, const void* p1,
                                        const void* p2, const void* p3,
                                        u32x4& a, u32x4& b, u32x4& c, u32x4& d) {
  asm volatile("global_load_dwordx4 %0, %4, off sc1\n\t"
               "global_load_dwordx4 %1, %5, off sc1\n\t"
               "global_load_dwordx4 %2, %6, off sc1\n\t"
               "global_load_dwordx4 %3, %7, off sc1\n\t"
               "s_waitcnt vmcnt(0)"
               : "=&v"(a), "=&v"(b), "=&v"(c), "=&v"(d)
               : "v"(p0), "v"(p1), "v"(p2), "v"(p3) : "memory");
}
__device__ __forceinline__ void ld8_sc1(const void* p0, const void* p1,
                                        const void* p2, const void* p3,
                                        const void* p4, const void* p5,
                                        const void* p6, const void* p7,
                                        u32x4& a, u32x4& b, u32x4& c, u32x4& d,
                                        u32x4& e, u32x4& f, u32x4& g, u32x4& h) {
  asm volatile("global_load_dwordx4 %0, %8, off sc1\n\t"
               "global_load_dwordx4 %1, %9, off sc1\n\t"
               "global_load_dwordx4 %2, %10, off sc1\n\t"
               "global_load_dwordx4 %3, %11, off sc1\n\t"
               "global_load_dwordx4 %4, %12, off sc1\n\t"
               "global_load_dwordx4 %5, %13, off sc1\n\t"
               "global_load_dwordx4 %6, %14, off sc1\n\t"
               "global_load_dwordx4 %7, %15, off sc1\n\t"
               "s_waitcnt vmcnt(0)"
               : "=&v"(a), "=&v"(b), "=&v"(c), "=&v"(d),
                 "=&v"(e), "=&v"(f), "=&v"(g), "=&v"(h)
               : "v"(p0), "v"(p1), "v"(p2), "v"(p3),
                 "v"(p4), "v"(p5), "v"(p6), "v"(p7) : "memory");
}
__device__ __forceinline__ void st_sc1_x4(void* p, u32x4 v) {
  asm volatile("global_store_dwordx4 %0, %1, off sc1" :: "v"(p), "v"(v) : "memory");
}

// ---------------------------------------------------------------------------
__global__ __launch_bounds__(256) void proj_kernel(
    const float* __restrict__ emb, const float* __restrict__ W_xh0,
    const float* __restrict__ b_xh0, float* __restrict__ proj) {
  int v = blockIdx.x >> 1;
  int j = ((blockIdx.x & 1) << 8) + threadIdx.x;
  float acc = b_xh0[j];
  const float* er = emb + v * NE;
  for (int e = 0; e < NE; ++e) acc += er[e] * W_xh0[e * NH + j];
  proj[v * NH + j] = acc;
}

__global__ __launch_bounds__(256) void transpose_bf16_kernel(
    const float* __restrict__ src, u16* __restrict__ dst, int R, int logC) {
  int idx = blockIdx.x * 256 + threadIdx.x;
  int C = 1 << logC;
  if (idx >= R * C) return;
  int r = idx >> logC;
  int c = idx & (C - 1);
  dst[c * R + r] = f2bf(src[idx]);
}

__global__ void zero_flags_kernel(int* flags) {
  int i = blockIdx.x * 256 + threadIdx.x;
  if (i < 2 * 64 * FS) flags[i] = 0;
}

__device__ __forceinline__ bf16x8v frag_A(const u16* __restrict__ buf,
                                          int kt, int lane) {
  return *(const bf16x8v*)(buf + (kt << 9) + (((lane ^ kt) & 63) << 3));
}

// wave-0 publish of the block's 16x64 rep slice into a group frag-panel:
// lane does chunks {lane, lane+64}; then vmcnt(0) + flag store (same wave).
__device__ __forceinline__ void publish_w0(const u16* __restrict__ rep,
                                           u16* __restrict__ gpanel,
                                           int sl, int lane) {
#pragma unroll
  for (int hh = 0; hh < 2; ++hh) {
    int c = hh * 64 + lane;
    int ktl = c >> 6, slot = c & 63;
    int ktp = sl * 2 + ktl;
    int v = (slot ^ ktp) & 63;
    int row = v & 15, koct = (v >> 4) & 3;
    int lc = ktl * 32 + koct * 8;
    st_sc1_x4(gpanel + ktp * 512 + slot * 8,
              *(const u32x4*)(rep + row * 64 + lc));
  }
}

// ---------------------------------------------------------------------------
__global__ __launch_bounds__(256, 1) void rnn_persist(
    const int* __restrict__ src, const int* __restrict__ lens,
    const float* __restrict__ proj,
    const u16* __restrict__ Wt_hh0,   // [NH][NH] = W^T, bf16
    const u16* __restrict__ Wt_xh1,
    const u16* __restrict__ Wt_hh1,
    const float* __restrict__ b_xh1,
    u16* __restrict__ h0f,            // [RING][GROUPS][8192] frag panels
    u16* __restrict__ h1f,            // [NT][GROUPS][8192] frag panels
    int* __restrict__ flags)          // flag0[64][FS] ++ flag1[64][FS]
{
  __shared__ struct {
    union {
      struct { __attribute__((aligned(16))) u16 a0[8192];
               float pj[NV][68]; int srcv[MR][NT]; } l0;
      struct { __attribute__((aligned(16))) u16 a0[8192];
               __attribute__((aligned(16))) u16 a1[8192]; } l1;
    } u;
    __attribute__((aligned(16))) u16 rep[16][64];
  } sm;

  const int bid = blockIdx.x;
  const bool is_l1 = (bid >= 64);
  const int rb = bid & 63;                 // role-local block id
  const int g = rb & (GROUPS - 1);
  const int sl = rb >> 3;
  const int c0 = sl * NCS;
  const int r0 = g * MR;

  const int tid = threadIdx.x;
  const int lane = tid & 63, wave = tid >> 6;
  const int lq = lane >> 4, lr = lane & 15;
  const int lcol = wave * 16 + lr;         // local col (0..63) this lane owns

  int* flag0 = flags;
  int* flag1 = flags + 64 * FS;
  int* myflag = (is_l1 ? flag1 : flag0) + rb * FS;

  int ln[4];
#pragma unroll
  for (int i = 0; i < 4; ++i) ln[i] = lens[r0 + lq * 4 + i];
  u16 oreg[4] = {0, 0, 0, 0};

  if (!is_l1) {
    // =========================== L0 pipeline =============================
    bf16x8v w0[16];
    {
      const u16* wp = Wt_hh0 + (size_t)(c0 + lcol) * NH + lq * 8;
#pragma unroll
      for (int kt = 0; kt < 16; ++kt) w0[kt] = *(const bf16x8v*)(wp + kt * 32);
    }
#pragma unroll
    for (int it = 0; it < 4; ++it) {       // pj slice: 64 x 64 f32
      int c = it * 256 + tid;
      int v = c >> 4, j4 = (c & 15) * 4;
      *(float4*)&sm.u.l0.pj[v][j4] = *(const float4*)&proj[v * NH + c0 + j4];
    }
#pragma unroll
    for (int it = 0; it < 8; ++it)         // src rows: 16 x 512 int
      ((int4*)sm.u.l0.srcv)[it * 256 + tid] =
          ((const int4*)(src + (size_t)r0 * NT))[it * 256 + tid];
    __syncthreads();

    for (int s = 0; s < NT; ++s) {
      f32x4v acc = {0.f, 0.f, 0.f, 0.f};
      if (s > 0) {
        // deps for this stage were polled during the previous stage's tail
        if (tid < 64) __builtin_amdgcn_fence(__ATOMIC_ACQUIRE, "agent");
        __syncthreads();
        {
          const u16* gp = h0f + ((size_t)((s - 1) & (RING - 1)) * GROUPS + g) * 8192;
          u32x4 a, b, c, d;
          ld4_sc1(gp + (tid + 0) * 8, gp + (tid + 256) * 8,
                  gp + (tid + 512) * 8, gp + (tid + 768) * 8, a, b, c, d);
          *(u32x4*)(sm.u.l0.a0 + (tid + 0) * 8) = a;
          *(u32x4*)(sm.u.l0.a0 + (tid + 256) * 8) = b;
          *(u32x4*)(sm.u.l0.a0 + (tid + 512) * 8) = c;
          *(u32x4*)(sm.u.l0.a0 + (tid + 768) * 8) = d;
        }
        __syncthreads();
#pragma unroll
        for (int kt = 0; kt < 16; ++kt)
          acc = __builtin_amdgcn_mfma_f32_16x16x32_bf16(
              frag_A(sm.u.l0.a0, kt, lane), w0[kt], acc, 0, 0, 0);
      }
#pragma unroll
      for (int i = 0; i < 4; ++i) {
        int row = lq * 4 + i;
        float pre = acc[i] + sm.u.l0.pj[sm.u.l0.srcv[row][s]][lcol];
        oreg[i] = (s < ln[i]) ? f2bf(tanhf(pre)) : oreg[i];
        sm.rep[row][lcol] = oreg[i];
      }
      __syncthreads();
      // ---- tail: publish (wave 0) || poll next-stage deps (waves 2,3) ----
      if (wave == 0) {
        publish_w0(&sm.rep[0][0],
                   h0f + ((size_t)(s & (RING - 1)) * GROUPS + g) * 8192, sl, lane);
        asm volatile("s_waitcnt vmcnt(0)" ::: "memory");
        if (lane == 0)
          __hip_atomic_store(myflag, s + 1, __ATOMIC_RELAXED,
                             __HIP_MEMORY_SCOPE_AGENT);
      } else if (wave == 2) {
        if (s + 1 < NT && lane < 8 && lane != sl) {
          const int* fp = flag0 + ((lane << 3) | g) * FS;
          while (__hip_atomic_load(fp, __ATOMIC_RELAXED,
                                   __HIP_MEMORY_SCOPE_AGENT) < s + 1) {}
        }
      } else if (wave == 3) {
        int need = s + 1 - 14;               // ring WAR for slot (s+1)&15
        if (s + 1 < NT && lane < 8 && need > 0) {
          const int* fp = flag1 + ((lane << 3) | g) * FS;
          while (__hip_atomic_load(fp, __ATOMIC_RELAXED,
                                   __HIP_MEMORY_SCOPE_AGENT) < need) {}
        }
      }
      __syncthreads();
    }
  } else {
    // =========================== L1 pipeline =============================
    bf16x8v wx[16], wh[16];
    {
      const u16* wpx = Wt_xh1 + (size_t)(c0 + lcol) * NH + lq * 8;
      const u16* wph = Wt_hh1 + (size_t)(c0 + lcol) * NH + lq * 8;
#pragma unroll
      for (int kt = 0; kt < 16; ++kt) {
        wx[kt] = *(const bf16x8v*)(wpx + kt * 32);
        wh[kt] = *(const bf16x8v*)(wph + kt * 32);
      }
    }
    const float bcol = b_xh1[c0 + lcol];
    __syncthreads();
    // pre-loop: h0(0) dependency (flag0 >= 1)
    if (tid < 8) {
      const int* fp = flag0 + ((tid << 3) | g) * FS;
      while (__hip_atomic_load(fp, __ATOMIC_RELAXED,
                               __HIP_MEMORY_SCOPE_AGENT) < 1) {}
    }
    __syncthreads();

    for (int t = 0; t < NT; ++t) {
      if (tid < 64) __builtin_amdgcn_fence(__ATOMIC_ACQUIRE, "agent");
      __syncthreads();
      {
        const u16* g0 = h0f + ((size_t)(t & (RING - 1)) * GROUPS + g) * 8192;
        if (t > 0) {
          const u16* g1 = h1f + ((size_t)(t - 1) * GROUPS + g) * 8192;
          u32x4 a, b, c, d, e, f, h, k;
          ld8_sc1(g0 + (tid + 0) * 8, g0 + (tid + 256) * 8,
                  g0 + (tid + 512) * 8, g0 + (tid + 768) * 8,
                  g1 + (tid + 0) * 8, g1 + (tid + 256) * 8,
                  g1 + (tid + 512) * 8, g1 + (tid + 768) * 8,
                  a, b, c, d, e, f, h, k);
          *(u32x4*)(sm.u.l1.a0 + (tid + 0) * 8) = a;
          *(u32x4*)(sm.u.l1.a0 + (tid + 256) * 8) = b;
          *(u32x4*)(sm.u.l1.a0 + (tid + 512) * 8) = c;
          *(u32x4*)(sm.u.l1.a0 + (tid + 768) * 8) = d;
          *(u32x4*)(sm.u.l1.a1 + (tid + 0) * 8) = e;
          *(u32x4*)(sm.u.l1.a1 + (tid + 256) * 8) = f;
          *(u32x4*)(sm.u.l1.a1 + (tid + 512) * 8) = h;
          *(u32x4*)(sm.u.l1.a1 + (tid + 768) * 8) = k;
        } else {
          u32x4 a, b, c, d;
          ld4_sc1(g0 + (tid + 0) * 8, g0 + (tid + 256) * 8,
                  g0 + (tid + 512) * 8, g0 + (tid + 768) * 8, a, b, c, d);
          *(u32x4*)(sm.u.l1.a0 + (tid + 0) * 8) = a;
          *(u32x4*)(sm.u.l1.a0 + (tid + 256) * 8) = b;
          *(u32x4*)(sm.u.l1.a0 + (tid + 512) * 8) = c;
          *(u32x4*)(sm.u.l1.a0 + (tid + 768) * 8) = d;
        }
      }
      __syncthreads();

      f32x4v accx = {0.f, 0.f, 0.f, 0.f}, acch = {0.f, 0.f, 0.f, 0.f};
#pragma unroll
      for (int kt = 0; kt < 16; ++kt)
        accx = __builtin_amdgcn_mfma_f32_16x16x32_bf16(
            frag_A(sm.u.l1.a0, kt, lane), wx[kt], accx, 0, 0, 0);
      if (t > 0) {
#pragma unroll
        for (int kt = 0; kt < 16; ++kt)
          acch = __builtin_amdgcn_mfma_f32_16x16x32_bf16(
              frag_A(sm.u.l1.a1, kt, lane), wh[kt], acch, 0, 0, 0);
      }
#pragma unroll
      for (int i = 0; i < 4; ++i) {
        int row = lq * 4 + i;
        float pre = accx[i] + acch[i] + bcol;
        oreg[i] = (t < ln[i]) ? f2bf(tanhf(pre)) : oreg[i];
        sm.rep[row][lcol] = oreg[i];
      }
      __syncthreads();
      // ---- tail: publish (wave 0) || poll next-stage deps (waves 2,3) ----
      if (wave == 0) {
        publish_w0(&sm.rep[0][0],
                   h1f + ((size_t)t * GROUPS + g) * 8192, sl, lane);
        asm volatile("s_waitcnt vmcnt(0)" ::: "memory");
        if (lane == 0)
          __hip_atomic_store(myflag, t + 1, __ATOMIC_RELAXED,
                             __HIP_MEMORY_SCOPE_AGENT);
      } else if (wave == 2) {
        if (t + 1 < NT && lane < 8 && lane != sl) {
          const int* fp = flag1 + ((lane << 3) | g) * FS;
          while (__hip_atomic_load(fp, __ATOMIC_RELAXED,
                                   __HIP_MEMORY_SCOPE_AGENT) < t + 1) {}
        }
      } else if (wave == 3) {
        if (t + 1 < NT && lane < 8) {
          const int* fp = flag0 + ((lane << 3) | g) * FS;
          while (__hip_atomic_load(fp, __ATOMIC_RELAXED,
                                   __HIP_MEMORY_SCOPE_AGENT) < t + 2) {}
        }
      }
      __syncthreads();
    }
  }
}

// ---------------------------------------------------------------------------
__global__ __launch_bounds__(256) void out_gemm(
    const u16* __restrict__ h1f, const u16* __restrict__ fc_wT,
    const float* __restrict__ fc_b, float* __restrict__ out)
{
  const int t = blockIdx.x;
  const int tid = threadIdx.x, lane = tid & 63, wave = tid >> 6;
  const int lq = lane >> 4, lr = lane & 15;
  const int m0 = wave * 32;
  f32x4v acc[2][8];
#pragma unroll
  for (int a = 0; a < 2; ++a)
#pragma unroll
    for (int b = 0; b < 8; ++b) acc[a][b] = (f32x4v){0.f, 0.f, 0.f, 0.f};

  const u16* p0 = h1f + ((size_t)t * GROUPS + wave * 2) * 8192;
  const u16* p1 = p0 + 8192;
#pragma unroll 2
  for (int kt = 0; kt < 16; ++kt) {
    bf16x8v a0 = *(const bf16x8v*)(p0 + kt * 512 + (((lane ^ kt) & 63) << 3));
    bf16x8v a1 = *(const bf16x8v*)(p1 + kt * 512 + (((lane ^ kt) & 63) << 3));
    int kb = kt * 32 + lq * 8;
#pragma unroll
    for (int ni = 0; ni < 8; ++ni) {
      bf16x8v bb = *(const bf16x8v*)(fc_wT + (size_t)(ni * 16 + lr) * NH + kb);
      acc[0][ni] = __builtin_amdgcn_mfma_f32_16x16x32_bf16(a0, bb, acc[0][ni], 0, 0, 0);
      acc[1][ni] = __builtin_amdgcn_mfma_f32_16x16x32_bf16(a1, bb, acc[1][ni], 0, 0, 0);
    }
  }
#pragma unroll
  for (int mi = 0; mi < 2; ++mi)
#pragma unroll
    for (int ni = 0; ni < 8; ++ni)
#pragma unroll
      for (int i = 0; i < 4; ++i) {
        int b_ = m0 + mi * 16 + lq * 4 + i;
        int p = ni * 16 + lr;
        out[((size_t)b_ * NT + t) * NP + p] = acc[mi][ni][i] + fc_b[p];
      }
}

// ---------------------------------------------------------------------------
extern "C" void kernel_launch(void* const* d_in, const int* in_sizes, int n_in,
                              void* d_out, int out_size, void* d_ws, size_t ws_size,
                              hipStream_t stream) {
  const int*   src   = (const int*)  d_in[0];
  const int*   lens  = (const int*)  d_in[1];
  const float* emb   = (const float*)d_in[2];
  const float* W_xh0 = (const float*)d_in[3];
  const float* b_xh0 = (const float*)d_in[4];
  const float* W_hh0 = (const float*)d_in[5];
  const float* W_xh1 = (const float*)d_in[6];
  const float* b_xh1 = (const float*)d_in[7];
  const float* W_hh1 = (const float*)d_in[8];
  const float* fc_w  = (const float*)d_in[9];
  const float* fc_b  = (const float*)d_in[10];
  float* out = (float*)d_out;

  char* ws = (char*)d_ws;
  auto alloc = [&](size_t bytes) { char* p = ws; ws += (bytes + 255) & ~size_t(255); return p; };
  float* proj   = (float*)alloc(NV * NH * 4);
  u16* Wt_hh0   = (u16*)  alloc(NH * NH * 2);
  u16* Wt_xh1   = (u16*)  alloc(NH * NH * 2);
  u16* Wt_hh1   = (u16*)  alloc(NH * NH * 2);
  u16* fc_wT    = (u16*)  alloc(NP * NH * 2);
  u16* h0f      = (u16*)  alloc((size_t)RING * GROUPS * 8192 * 2);
  u16* h1f      = (u16*)  alloc((size_t)NT * GROUPS * 8192 * 2);
  int* flags    = (int*)  alloc(2 * 64 * FS * 4);

  proj_kernel<<<NV * 2, 256, 0, stream>>>(emb, W_xh0, b_xh0, proj);
  transpose_bf16_kernel<<<(NH * NH + 255) / 256, 256, 0, stream>>>(W_hh0, Wt_hh0, NH, 9);
  transpose_bf16_kernel<<<(NH * NH + 255) / 256, 256, 0, stream>>>(W_xh1, Wt_xh1, NH, 9);
  transpose_bf16_kernel<<<(NH * NH + 255) / 256, 256, 0, stream>>>(W_hh1, Wt_hh1, NH, 9);
  transpose_bf16_kernel<<<(NH * NP + 255) / 256, 256, 0, stream>>>(fc_w, fc_wT, NH, 7);
  zero_flags_kernel<<<(2 * 64 * FS + 255) / 256, 256, 0, stream>>>(flags);

  {
    void* kargs[] = { (void*)&src, (void*)&lens, (void*)&proj, (void*)&Wt_hh0,
                      (void*)&Wt_xh1, (void*)&Wt_hh1, (void*)&b_xh1,
                      (void*)&h0f, (void*)&h1f, (void*)&flags };
    hipError_t e = hipLaunchCooperativeKernel((void*)rnn_persist, dim3(NBLK), dim3(256),
                                              kargs, 0, stream);
    if (e != hipSuccess) {
      rnn_persist<<<NBLK, 256, 0, stream>>>(src, lens, proj, Wt_hh0, Wt_xh1,
                                            Wt_hh1, b_xh1, h0f, h1f, flags);
    }
  }

  out_gemm<<<NT, 256, 0, stream>>>(h1f, fc_wT, fc_b, out);
}